// Round 1
// baseline (7597.555 us; speedup 1.0000x reference)
//
#include <hip/hip_runtime.h>

// Problem constants (also derived from in_sizes at launch for safety)
#define F_IN 35
#define F_OUT 5
#define HID 100

// ---------------------------------------------------------------------------
// Weight prep: build packed/combined projection matrices.
// dconv(X,W,b) = X@(W00+W10-W02-W12) + Pf(X@W01) + Pb(X@W11)
//               + 2*Pf(Pf(X@W02)) + 2*Pb(Pb(X@W12)) + b
// WpackA [40 x 50]: cols 0-4 Dz, 5-9 Dr, 10-14 Fz1, 15-19 Fr1, 20-24 Fz2,
//                   25-29 Fr2, 30-34 Bz1, 35-39 Br1, 40-44 Bz2, 45-49 Br2
// WpackC [40 x 25]: cols 0-4 Dh, 5-9 Fh1, 10-14 Fh2, 15-19 Bh1, 20-24 Bh2
// ---------------------------------------------------------------------------
__global__ __launch_bounds__(256) void prep_weights(
    const float* __restrict__ Wz, const float* __restrict__ Wr,
    const float* __restrict__ Wh,
    float* __restrict__ WpackA, float* __restrict__ WpackC) {
  int t = blockIdx.x * blockDim.x + threadIdx.x;
  if (t < 40 * 50) {
    int i = t / 50, c = t % 50;
    auto W = [&](const float* Wp, int d, int k, int o) {
      return Wp[((d * 3 + k) * 40 + i) * 5 + o];
    };
    float v;
    if (c < 5)       v = W(Wz,0,0,c)    + W(Wz,1,0,c)    - W(Wz,0,2,c)    - W(Wz,1,2,c);
    else if (c < 10) v = W(Wr,0,0,c-5)  + W(Wr,1,0,c-5)  - W(Wr,0,2,c-5)  - W(Wr,1,2,c-5);
    else if (c < 15) v = W(Wz,0,1,c-10);
    else if (c < 20) v = W(Wr,0,1,c-15);
    else if (c < 25) v = W(Wz,0,2,c-20);
    else if (c < 30) v = W(Wr,0,2,c-25);
    else if (c < 35) v = W(Wz,1,1,c-30);
    else if (c < 40) v = W(Wr,1,1,c-35);
    else if (c < 45) v = W(Wz,1,2,c-40);
    else             v = W(Wr,1,2,c-45);
    WpackA[i * 50 + c] = v;
  }
  if (t < 40 * 25) {
    int i = t / 25, c = t % 25;
    auto W = [&](const float* Wp, int d, int k, int o) {
      return Wp[((d * 3 + k) * 40 + i) * 5 + o];
    };
    float v;
    if (c < 5)       v = W(Wh,0,0,c)    + W(Wh,1,0,c)    - W(Wh,0,2,c)    - W(Wh,1,2,c);
    else if (c < 10) v = W(Wh,0,1,c-5);
    else if (c < 15) v = W(Wh,0,2,c-10);
    else if (c < 20) v = W(Wh,1,1,c-15);
    else             v = W(Wh,1,2,c-20);
    WpackC[i * 25 + c] = v;
  }
}

// ---------------------------------------------------------------------------
// Degree accumulation (deg arrays pre-zeroed via memset)
// ---------------------------------------------------------------------------
__global__ __launch_bounds__(256) void degrees_kernel(
    const int* __restrict__ ei, const float* __restrict__ w,
    float* __restrict__ deg_out, float* __restrict__ deg_in, int E) {
  int e = blockIdx.x * blockDim.x + threadIdx.x;
  if (e >= E) return;
  int s = ei[e], d = ei[E + e];
  float ww = w[e];
  atomicAdd(&deg_out[s], ww);
  atomicAdd(&deg_in[d], ww);
}

// ---------------------------------------------------------------------------
// Normalized edge weights. w_fwd goes straight to d_out (it is output A).
// ---------------------------------------------------------------------------
__global__ __launch_bounds__(256) void norm_w_kernel(
    const int* __restrict__ ei, const float* __restrict__ w,
    const float* __restrict__ deg_out, const float* __restrict__ deg_in,
    float* __restrict__ wf, float* __restrict__ wb, int E) {
  int e = blockIdx.x * blockDim.x + threadIdx.x;
  if (e >= E) return;
  int s = ei[e], d = ei[E + e];
  float ww = w[e];
  wf[e] = ww / fmaxf(deg_out[s], 1e-12f);
  wb[e] = ww / fmaxf(deg_in[d], 1e-12f);
}

// ---------------------------------------------------------------------------
// Node phase A: MLP (h1) + XH projections (direct terms + prop inputs)
// ---------------------------------------------------------------------------
__global__ __launch_bounds__(256) void nodeA_kernel(
    const float* __restrict__ x,
    const float* __restrict__ W1, const float* __restrict__ b1,
    const float* __restrict__ W2, const float* __restrict__ b2,
    const float* __restrict__ bz, const float* __restrict__ br,
    const float* __restrict__ WpackA,
    float* __restrict__ h1, float* __restrict__ accDz,
    float* __restrict__ accDr, float* __restrict__ Pf,
    float* __restrict__ Pb, int N) {
  int n = blockIdx.x * blockDim.x + threadIdx.x;
  if (n >= N) return;
  float xv[40];
  const float* xr = x + (size_t)n * F_IN;
  #pragma unroll
  for (int i = 0; i < F_IN; i++) xv[i] = xr[i];

  // MLP: h1 = relu(x@W1+b1)@W2 + b2
  float h5[5];
  #pragma unroll
  for (int o = 0; o < 5; o++) h5[o] = b2[o];
  for (int hh = 0; hh < HID; hh++) {
    float t = b1[hh];
    #pragma unroll
    for (int i = 0; i < F_IN; i++) t += xv[i] * W1[i * HID + hh];
    t = fmaxf(t, 0.f);
    #pragma unroll
    for (int o = 0; o < 5; o++) h5[o] += t * W2[hh * 5 + o];
  }
  #pragma unroll
  for (int o = 0; o < 5; o++) {
    h1[(size_t)n * 5 + o] = h5[o];
    xv[F_IN + o] = h5[o];
  }

  // XH @ WpackA  (50 columns)
  float acc[50];
  #pragma unroll
  for (int c = 0; c < 50; c++) acc[c] = 0.f;
  for (int i = 0; i < 40; i++) {
    float xi = xv[i];
    #pragma unroll
    for (int c = 0; c < 50; c++) acc[c] += xi * WpackA[i * 50 + c];
  }
  #pragma unroll
  for (int o = 0; o < 5; o++) {
    accDz[(size_t)n * 5 + o] = acc[o] + bz[o];
    accDr[(size_t)n * 5 + o] = acc[5 + o] + br[o];
  }
  #pragma unroll
  for (int c = 0; c < 20; c++) Pf[(size_t)n * 20 + c] = acc[10 + c];
  #pragma unroll
  for (int c = 0; c < 20; c++) Pb[(size_t)n * 20 + c] = acc[30 + c];
}

// ---------------------------------------------------------------------------
// Generic edge propagation: out[to] += wn * in[from]  (out pre-zeroed)
// ---------------------------------------------------------------------------
template <int C>
__global__ __launch_bounds__(256) void prop_kernel(
    const int* __restrict__ from, const int* __restrict__ to,
    const float* __restrict__ wn, const float* __restrict__ in, int ldin,
    float* __restrict__ out, int E) {
  int e = blockIdx.x * blockDim.x + threadIdx.x;
  if (e >= E) return;
  int s = from[e], d = to[e];
  float ww = wn[e];
  const float* ir = in + (size_t)s * ldin;
  float* orw = out + (size_t)d * C;
  #pragma unroll
  for (int c = 0; c < C; c++) atomicAdd(&orw[c], ww * ir[c]);
}

// ---------------------------------------------------------------------------
// Node phase B: Z,R gates + XHr projections
// Qf/Qb rows: 20 wide (cols 0-4 z 1-hop, 5-9 r 1-hop, 10-19 2-hop inputs)
// Rf/Rb rows: 10 wide (cols 0-4 z 2-hop, 5-9 r 2-hop)
// ---------------------------------------------------------------------------
__global__ __launch_bounds__(256) void nodeB_kernel(
    const float* __restrict__ x, const float* __restrict__ h1,
    const float* __restrict__ accDz, const float* __restrict__ accDr,
    const float* __restrict__ Qf, const float* __restrict__ Qb,
    const float* __restrict__ Rf, const float* __restrict__ Rb,
    const float* __restrict__ bh, const float* __restrict__ WpackC,
    float* __restrict__ Zg, float* __restrict__ accDh,
    float* __restrict__ Pfh, float* __restrict__ Pbh, int N) {
  int n = blockIdx.x * blockDim.x + threadIdx.x;
  if (n >= N) return;
  float r[5];
  #pragma unroll
  for (int o = 0; o < 5; o++) {
    float zp = accDz[(size_t)n * 5 + o] + Qf[(size_t)n * 20 + o] +
               Qb[(size_t)n * 20 + o] + 2.f * Rf[(size_t)n * 10 + o] +
               2.f * Rb[(size_t)n * 10 + o];
    float rp = accDr[(size_t)n * 5 + o] + Qf[(size_t)n * 20 + 5 + o] +
               Qb[(size_t)n * 20 + 5 + o] + 2.f * Rf[(size_t)n * 10 + 5 + o] +
               2.f * Rb[(size_t)n * 10 + 5 + o];
    float z = 1.f / (1.f + __expf(-zp));
    r[o] = 1.f / (1.f + __expf(-rp));
    Zg[(size_t)n * 5 + o] = z;
  }
  float xv[40];
  const float* xr = x + (size_t)n * F_IN;
  #pragma unroll
  for (int i = 0; i < F_IN; i++) xv[i] = xr[i];
  #pragma unroll
  for (int o = 0; o < 5; o++) xv[F_IN + o] = h1[(size_t)n * 5 + o] * r[o];

  float acc[25];
  #pragma unroll
  for (int c = 0; c < 25; c++) acc[c] = 0.f;
  for (int i = 0; i < 40; i++) {
    float xi = xv[i];
    #pragma unroll
    for (int c = 0; c < 25; c++) acc[c] += xi * WpackC[i * 25 + c];
  }
  #pragma unroll
  for (int o = 0; o < 5; o++) accDh[(size_t)n * 5 + o] = acc[o] + bh[o];
  #pragma unroll
  for (int c = 0; c < 10; c++) {
    Pfh[(size_t)n * 10 + c] = acc[5 + c];
    Pbh[(size_t)n * 10 + c] = acc[15 + c];
  }
}

// ---------------------------------------------------------------------------
// Node phase C: H_tilde, H, y
// ---------------------------------------------------------------------------
__global__ __launch_bounds__(256) void nodeC_kernel(
    const float* __restrict__ h1, const float* __restrict__ Zg,
    const float* __restrict__ accDh,
    const float* __restrict__ Qfh, const float* __restrict__ Qbh,
    const float* __restrict__ Rfh, const float* __restrict__ Rbh,
    const float* __restrict__ Wl, const float* __restrict__ bl,
    float* __restrict__ y, int N) {
  int n = blockIdx.x * blockDim.x + threadIdx.x;
  if (n >= N) return;
  float acc = bl[0];
  #pragma unroll
  for (int o = 0; o < 5; o++) {
    float pre = accDh[(size_t)n * 5 + o] + Qfh[(size_t)n * 10 + o] +
                Qbh[(size_t)n * 10 + o] + 2.f * Rfh[(size_t)n * 5 + o] +
                2.f * Rbh[(size_t)n * 5 + o];
    float ht = tanhf(pre);
    float z = Zg[(size_t)n * 5 + o];
    float H = z * h1[(size_t)n * 5 + o] + (1.f - z) * ht;
    acc += fmaxf(H, 0.f) * Wl[o];
  }
  y[n] = acc;
}

// ---------------------------------------------------------------------------
extern "C" void kernel_launch(void* const* d_in, const int* in_sizes, int n_in,
                              void* d_out, int out_size, void* d_ws, size_t ws_size,
                              hipStream_t stream) {
  const float* x  = (const float*)d_in[0];
  const int*   ei = (const int*)d_in[1];
  const float* ew = (const float*)d_in[2];
  const float* W1 = (const float*)d_in[3];
  const float* b1 = (const float*)d_in[4];
  const float* W2 = (const float*)d_in[5];
  const float* b2 = (const float*)d_in[6];
  const float* Wz = (const float*)d_in[7];
  const float* bz = (const float*)d_in[8];
  const float* Wr = (const float*)d_in[9];
  const float* br = (const float*)d_in[10];
  const float* Wh = (const float*)d_in[11];
  const float* bh = (const float*)d_in[12];
  const float* Wl = (const float*)d_in[13];
  const float* bl = (const float*)d_in[14];

  const int N = in_sizes[0] / F_IN;
  const int E = in_sizes[2];

  float* out = (float*)d_out;
  float* y_out  = out;          // [N]
  float* wf_out = out + N;      // [E]  == output A

  // Workspace layout (floats)
  float* W = (float*)d_ws;
  size_t o = 0;
  float* deg_out = W + o; o += N;
  float* deg_in  = W + o; o += N;
  float* w_bwd   = W + o; o += E;
  float* h1      = W + o; o += (size_t)5 * N;
  float* accDz   = W + o; o += (size_t)5 * N;
  float* accDr   = W + o; o += (size_t)5 * N;
  float* accDh   = W + o; o += (size_t)5 * N;
  float* Zg      = W + o; o += (size_t)5 * N;
  float* Pf      = W + o; o += (size_t)20 * N;
  float* Pb      = W + o; o += (size_t)20 * N;
  float* Qf      = W + o; o += (size_t)20 * N;   // QR region start
  float* Qb      = W + o; o += (size_t)20 * N;
  float* Rf      = W + o; o += (size_t)10 * N;
  float* Rb      = W + o; o += (size_t)10 * N;
  float* WpackA  = W + o; o += 2000;
  float* WpackC  = W + o; o += 1000;

  // Phase-C aliases (regions free by then)
  float* Pfh = Pf; float* Pbh = Pb;
  float* Qfh = Qf; float* Qbh = Qb;
  float* Rfh = Rf; float* Rbh = Rb;

  const int* src = ei;
  const int* dst = ei + E;

  const int EB = (E + 255) / 256;
  const int NB = (N + 255) / 256;

  // 1. packed weights
  prep_weights<<<8, 256, 0, stream>>>(Wz, Wr, Wh, WpackA, WpackC);

  // 2. degrees
  hipMemsetAsync(deg_out, 0, (size_t)2 * N * sizeof(float), stream);
  degrees_kernel<<<EB, 256, 0, stream>>>(ei, ew, deg_out, deg_in, E);

  // 3. normalized weights (wf -> output A)
  norm_w_kernel<<<EB, 256, 0, stream>>>(ei, ew, deg_out, deg_in, wf_out, w_bwd, E);

  // 4. node phase A
  nodeA_kernel<<<NB, 256, 0, stream>>>(x, W1, b1, W2, b2, bz, br, WpackA,
                                       h1, accDz, accDr, Pf, Pb, N);

  // 5. phase-A propagation
  hipMemsetAsync(Qf, 0, (size_t)60 * N * sizeof(float), stream);
  prop_kernel<20><<<EB, 256, 0, stream>>>(src, dst, wf_out, Pf, 20, Qf, E);
  prop_kernel<20><<<EB, 256, 0, stream>>>(dst, src, w_bwd, Pb, 20, Qb, E);
  prop_kernel<10><<<EB, 256, 0, stream>>>(src, dst, wf_out, Qf + 10, 20, Rf, E);
  prop_kernel<10><<<EB, 256, 0, stream>>>(dst, src, w_bwd, Qb + 10, 20, Rb, E);

  // 6. gates + XHr projections
  nodeB_kernel<<<NB, 256, 0, stream>>>(x, h1, accDz, accDr, Qf, Qb, Rf, Rb,
                                       bh, WpackC, Zg, accDh, Pfh, Pbh, N);

  // 7. phase-C propagation
  hipMemsetAsync(Qf, 0, (size_t)60 * N * sizeof(float), stream);
  prop_kernel<10><<<EB, 256, 0, stream>>>(src, dst, wf_out, Pfh, 10, Qfh, E);
  prop_kernel<10><<<EB, 256, 0, stream>>>(dst, src, w_bwd, Pbh, 10, Qbh, E);
  prop_kernel<5><<<EB, 256, 0, stream>>>(src, dst, wf_out, Qfh + 5, 10, Rfh, E);
  prop_kernel<5><<<EB, 256, 0, stream>>>(dst, src, w_bwd, Qbh + 5, 10, Rbh, E);

  // 8. final
  nodeC_kernel<<<NB, 256, 0, stream>>>(h1, Zg, accDh, Qfh, Qbh, Rfh, Rbh,
                                       Wl, bl, y_out, N);
}

// Round 2
// 1118.753 us; speedup vs baseline: 6.7911x; 6.7911x over previous
//
#include <hip/hip_runtime.h>

#define F_IN 35
#define F_OUT 5
#define HID 100

// ---------------------------------------------------------------------------
// Weight prep: packed/combined projection matrices.
// dconv(X,W,b) = X@(W00+W10-W02-W12) + Pf(X@W01) + Pb(X@W11)
//               + 2*Pf(Pf(X@W02)) + 2*Pb(Pb(X@W12)) + b
// WpackA [40 x 50]: cols 0-4 Dz, 5-9 Dr, 10-14 Fz1, 15-19 Fr1, 20-24 Fz2,
//                   25-29 Fr2, 30-34 Bz1, 35-39 Br1, 40-44 Bz2, 45-49 Br2
// WpackC [40 x 25]: cols 0-4 Dh, 5-9 Fh1, 10-14 Fh2, 15-19 Bh1, 20-24 Bh2
// ---------------------------------------------------------------------------
__global__ __launch_bounds__(256) void prep_weights(
    const float* __restrict__ Wz, const float* __restrict__ Wr,
    const float* __restrict__ Wh,
    float* __restrict__ WpackA, float* __restrict__ WpackC) {
  int t = blockIdx.x * blockDim.x + threadIdx.x;
  if (t < 40 * 50) {
    int i = t / 50, c = t % 50;
    auto W = [&](const float* Wp, int d, int k, int o) {
      return Wp[((d * 3 + k) * 40 + i) * 5 + o];
    };
    float v;
    if (c < 5)       v = W(Wz,0,0,c)    + W(Wz,1,0,c)    - W(Wz,0,2,c)    - W(Wz,1,2,c);
    else if (c < 10) v = W(Wr,0,0,c-5)  + W(Wr,1,0,c-5)  - W(Wr,0,2,c-5)  - W(Wr,1,2,c-5);
    else if (c < 15) v = W(Wz,0,1,c-10);
    else if (c < 20) v = W(Wr,0,1,c-15);
    else if (c < 25) v = W(Wz,0,2,c-20);
    else if (c < 30) v = W(Wr,0,2,c-25);
    else if (c < 35) v = W(Wz,1,1,c-30);
    else if (c < 40) v = W(Wr,1,1,c-35);
    else if (c < 45) v = W(Wz,1,2,c-40);
    else             v = W(Wr,1,2,c-45);
    WpackA[i * 50 + c] = v;
  }
  if (t < 40 * 25) {
    int i = t / 25, c = t % 25;
    auto W = [&](const float* Wp, int d, int k, int o) {
      return Wp[((d * 3 + k) * 40 + i) * 5 + o];
    };
    float v;
    if (c < 5)       v = W(Wh,0,0,c)    + W(Wh,1,0,c)    - W(Wh,0,2,c)    - W(Wh,1,2,c);
    else if (c < 10) v = W(Wh,0,1,c-5);
    else if (c < 15) v = W(Wh,0,2,c-10);
    else if (c < 20) v = W(Wh,1,1,c-15);
    else             v = W(Wh,1,2,c-20);
    WpackC[i * 25 + c] = v;
  }
}

// ---------------------------------------------------------------------------
// Degrees (float) + CSR histogram counts (int). All outputs pre-zeroed.
// ---------------------------------------------------------------------------
__global__ __launch_bounds__(256) void degcnt_kernel(
    const int* __restrict__ ei, const float* __restrict__ w,
    float* __restrict__ deg_out, float* __restrict__ deg_in,
    int* __restrict__ cnt_dst, int* __restrict__ cnt_src, int E) {
  int e = blockIdx.x * blockDim.x + threadIdx.x;
  if (e >= E) return;
  int s = ei[e], d = ei[E + e];
  float ww = w[e];
  atomicAdd(&deg_out[s], ww);
  atomicAdd(&deg_in[d], ww);
  atomicAdd(&cnt_src[s], 1);
  atomicAdd(&cnt_dst[d], 1);
}

// ---------------------------------------------------------------------------
// Two-array exclusive scan: block 0 scans cnt_dst -> rs_fwd/cur_fwd,
// block 1 scans cnt_src -> rs_bwd/cur_bwd. 1024 threads/block.
// ---------------------------------------------------------------------------
__global__ __launch_bounds__(1024) void scan_kernel(
    const int* __restrict__ cnt_dst, const int* __restrict__ cnt_src,
    int* __restrict__ rs_fwd, int* __restrict__ cur_fwd,
    int* __restrict__ rs_bwd, int* __restrict__ cur_bwd, int N) {
  const int* cnt = (blockIdx.x == 0) ? cnt_dst : cnt_src;
  int* rs  = (blockIdx.x == 0) ? rs_fwd  : rs_bwd;
  int* cur = (blockIdx.x == 0) ? cur_fwd : cur_bwd;
  __shared__ int lsum[1024];
  int t = threadIdx.x;
  int chunk = (N + 1023) / 1024;
  int lo = t * chunk, hi = min(lo + chunk, N);
  if (lo > N) lo = N;
  if (hi < lo) hi = lo;
  int s = 0;
  for (int i = lo; i < hi; i++) s += cnt[i];
  lsum[t] = s;
  __syncthreads();
  for (int off = 1; off < 1024; off <<= 1) {
    int v = (t >= off) ? lsum[t - off] : 0;
    __syncthreads();
    lsum[t] += v;
    __syncthreads();
  }
  int run = (t == 0) ? 0 : lsum[t - 1];
  for (int i = lo; i < hi; i++) { rs[i] = run; cur[i] = run; run += cnt[i]; }
  if (t == 1023) rs[N] = run;
}

// ---------------------------------------------------------------------------
// Scatter edges into both CSRs; weight folded into adjacency entry.
// Also emits w_fwd straight into d_out (it is output A).
// adj_fwd: lists by dst, entry (src, w_fwd)  -> used by prop_fwd gather
// adj_bwd: lists by src, entry (dst, w_bwd)  -> used by prop_bwd gather
// ---------------------------------------------------------------------------
__global__ __launch_bounds__(256) void scatter_kernel(
    const int* __restrict__ ei, const float* __restrict__ w,
    const float* __restrict__ deg_out, const float* __restrict__ deg_in,
    int* __restrict__ cur_fwd, int* __restrict__ cur_bwd,
    int2* __restrict__ adj_fwd, int2* __restrict__ adj_bwd,
    float* __restrict__ wf_out, int E) {
  int e = blockIdx.x * blockDim.x + threadIdx.x;
  if (e >= E) return;
  int s = ei[e], d = ei[E + e];
  float ww = w[e];
  float wf = ww / fmaxf(deg_out[s], 1e-12f);
  float wb = ww / fmaxf(deg_in[d], 1e-12f);
  wf_out[e] = wf;
  int pf = atomicAdd(&cur_fwd[d], 1);
  adj_fwd[pf] = make_int2(s, __float_as_int(wf));
  int pb = atomicAdd(&cur_bwd[s], 1);
  adj_bwd[pb] = make_int2(d, __float_as_int(wb));
}

// ---------------------------------------------------------------------------
// Gather propagation: out[n][0..C) = sum_{(m,w) in adj[n]} w * in[m][0..C)
// No atomics; coalesced writes; source rows are L2/L3-resident.
// ---------------------------------------------------------------------------
template <int C>
__global__ __launch_bounds__(256) void gprop_kernel(
    const int* __restrict__ rowstart, const int2* __restrict__ adj,
    const float* __restrict__ in, int ldin,
    float* __restrict__ out, int N) {
  int n = blockIdx.x * blockDim.x + threadIdx.x;
  if (n >= N) return;
  int i0 = rowstart[n], i1 = rowstart[n + 1];
  float acc[C];
  #pragma unroll
  for (int c = 0; c < C; c++) acc[c] = 0.f;
  for (int i = i0; i < i1; i++) {
    int2 a = adj[i];
    float ww = __int_as_float(a.y);
    const float* row = in + (size_t)a.x * ldin;
    #pragma unroll
    for (int c = 0; c < C; c++) acc[c] = fmaf(ww, row[c], acc[c]);
  }
  float* orow = out + (size_t)n * C;
  #pragma unroll
  for (int c = 0; c < C; c++) orow[c] = acc[c];
}

// ---------------------------------------------------------------------------
// Node phase A: MLP (h1) + XH projections (direct terms + prop inputs)
// ---------------------------------------------------------------------------
__global__ __launch_bounds__(256) void nodeA_kernel(
    const float* __restrict__ x,
    const float* __restrict__ W1, const float* __restrict__ b1,
    const float* __restrict__ W2, const float* __restrict__ b2,
    const float* __restrict__ bz, const float* __restrict__ br,
    const float* __restrict__ WpackA,
    float* __restrict__ h1, float* __restrict__ accDz,
    float* __restrict__ accDr, float* __restrict__ Pf,
    float* __restrict__ Pb, int N) {
  int n = blockIdx.x * blockDim.x + threadIdx.x;
  if (n >= N) return;
  float xv[40];
  const float* xr = x + (size_t)n * F_IN;
  #pragma unroll
  for (int i = 0; i < F_IN; i++) xv[i] = xr[i];

  float h5[5];
  #pragma unroll
  for (int o = 0; o < 5; o++) h5[o] = b2[o];
  for (int hh = 0; hh < HID; hh++) {
    float t = b1[hh];
    #pragma unroll
    for (int i = 0; i < F_IN; i++) t += xv[i] * W1[i * HID + hh];
    t = fmaxf(t, 0.f);
    #pragma unroll
    for (int o = 0; o < 5; o++) h5[o] += t * W2[hh * 5 + o];
  }
  #pragma unroll
  for (int o = 0; o < 5; o++) {
    h1[(size_t)n * 5 + o] = h5[o];
    xv[F_IN + o] = h5[o];
  }

  float acc[50];
  #pragma unroll
  for (int c = 0; c < 50; c++) acc[c] = 0.f;
  for (int i = 0; i < 40; i++) {
    float xi = xv[i];
    #pragma unroll
    for (int c = 0; c < 50; c++) acc[c] += xi * WpackA[i * 50 + c];
  }
  #pragma unroll
  for (int o = 0; o < 5; o++) {
    accDz[(size_t)n * 5 + o] = acc[o] + bz[o];
    accDr[(size_t)n * 5 + o] = acc[5 + o] + br[o];
  }
  #pragma unroll
  for (int c = 0; c < 20; c++) Pf[(size_t)n * 20 + c] = acc[10 + c];
  #pragma unroll
  for (int c = 0; c < 20; c++) Pb[(size_t)n * 20 + c] = acc[30 + c];
}

// ---------------------------------------------------------------------------
// Node phase B: Z,R gates + XHr projections
// ---------------------------------------------------------------------------
__global__ __launch_bounds__(256) void nodeB_kernel(
    const float* __restrict__ x, const float* __restrict__ h1,
    const float* __restrict__ accDz, const float* __restrict__ accDr,
    const float* __restrict__ Qf, const float* __restrict__ Qb,
    const float* __restrict__ Rf, const float* __restrict__ Rb,
    const float* __restrict__ bh, const float* __restrict__ WpackC,
    float* __restrict__ Zg, float* __restrict__ accDh,
    float* __restrict__ Pfh, float* __restrict__ Pbh, int N) {
  int n = blockIdx.x * blockDim.x + threadIdx.x;
  if (n >= N) return;
  float r[5];
  #pragma unroll
  for (int o = 0; o < 5; o++) {
    float zp = accDz[(size_t)n * 5 + o] + Qf[(size_t)n * 20 + o] +
               Qb[(size_t)n * 20 + o] + 2.f * Rf[(size_t)n * 10 + o] +
               2.f * Rb[(size_t)n * 10 + o];
    float rp = accDr[(size_t)n * 5 + o] + Qf[(size_t)n * 20 + 5 + o] +
               Qb[(size_t)n * 20 + 5 + o] + 2.f * Rf[(size_t)n * 10 + 5 + o] +
               2.f * Rb[(size_t)n * 10 + 5 + o];
    float z = 1.f / (1.f + __expf(-zp));
    r[o] = 1.f / (1.f + __expf(-rp));
    Zg[(size_t)n * 5 + o] = z;
  }
  float xv[40];
  const float* xr = x + (size_t)n * F_IN;
  #pragma unroll
  for (int i = 0; i < F_IN; i++) xv[i] = xr[i];
  #pragma unroll
  for (int o = 0; o < 5; o++) xv[F_IN + o] = h1[(size_t)n * 5 + o] * r[o];

  float acc[25];
  #pragma unroll
  for (int c = 0; c < 25; c++) acc[c] = 0.f;
  for (int i = 0; i < 40; i++) {
    float xi = xv[i];
    #pragma unroll
    for (int c = 0; c < 25; c++) acc[c] += xi * WpackC[i * 25 + c];
  }
  #pragma unroll
  for (int o = 0; o < 5; o++) accDh[(size_t)n * 5 + o] = acc[o] + bh[o];
  #pragma unroll
  for (int c = 0; c < 10; c++) {
    Pfh[(size_t)n * 10 + c] = acc[5 + c];
    Pbh[(size_t)n * 10 + c] = acc[15 + c];
  }
}

// ---------------------------------------------------------------------------
// Node phase C: H_tilde, H, y
// ---------------------------------------------------------------------------
__global__ __launch_bounds__(256) void nodeC_kernel(
    const float* __restrict__ h1, const float* __restrict__ Zg,
    const float* __restrict__ accDh,
    const float* __restrict__ Qfh, const float* __restrict__ Qbh,
    const float* __restrict__ Rfh, const float* __restrict__ Rbh,
    const float* __restrict__ Wl, const float* __restrict__ bl,
    float* __restrict__ y, int N) {
  int n = blockIdx.x * blockDim.x + threadIdx.x;
  if (n >= N) return;
  float acc = bl[0];
  #pragma unroll
  for (int o = 0; o < 5; o++) {
    float pre = accDh[(size_t)n * 5 + o] + Qfh[(size_t)n * 10 + o] +
                Qbh[(size_t)n * 10 + o] + 2.f * Rfh[(size_t)n * 5 + o] +
                2.f * Rbh[(size_t)n * 5 + o];
    float ht = tanhf(pre);
    float z = Zg[(size_t)n * 5 + o];
    float H = z * h1[(size_t)n * 5 + o] + (1.f - z) * ht;
    acc += fmaxf(H, 0.f) * Wl[o];
  }
  y[n] = acc;
}

// ---------------------------------------------------------------------------
extern "C" void kernel_launch(void* const* d_in, const int* in_sizes, int n_in,
                              void* d_out, int out_size, void* d_ws, size_t ws_size,
                              hipStream_t stream) {
  const float* x  = (const float*)d_in[0];
  const int*   ei = (const int*)d_in[1];
  const float* ew = (const float*)d_in[2];
  const float* W1 = (const float*)d_in[3];
  const float* b1 = (const float*)d_in[4];
  const float* W2 = (const float*)d_in[5];
  const float* b2 = (const float*)d_in[6];
  const float* Wz = (const float*)d_in[7];
  const float* bz = (const float*)d_in[8];
  const float* Wr = (const float*)d_in[9];
  const float* br = (const float*)d_in[10];
  const float* Wh = (const float*)d_in[11];
  const float* bh = (const float*)d_in[12];
  const float* Wl = (const float*)d_in[13];
  const float* bl = (const float*)d_in[14];

  const int N = in_sizes[0] / F_IN;
  const int E = in_sizes[2];

  float* out = (float*)d_out;
  float* y_out  = out;          // [N]
  float* wf_out = out + N;      // [E]  == output A

  // Workspace layout
  float* W = (float*)d_ws;
  size_t o = 0;
  float* deg_out = W + o; o += N;            // |
  float* deg_in  = W + o; o += N;            // | zeroed as one 4N block
  int* cnt_dst   = (int*)(W + o); o += N;    // |
  int* cnt_src   = (int*)(W + o); o += N;    // |
  int* rs_fwd    = (int*)(W + o); o += N + 1;
  int* rs_bwd    = (int*)(W + o); o += N + 1;
  int* cur_fwd   = (int*)(W + o); o += N;
  int* cur_bwd   = (int*)(W + o); o += N;
  o = (o + 1) & ~(size_t)1;                  // 8B align for int2
  int2* adj_fwd  = (int2*)(W + o); o += 2 * (size_t)E;
  int2* adj_bwd  = (int2*)(W + o); o += 2 * (size_t)E;
  float* h1      = W + o; o += (size_t)5 * N;
  float* accDz   = W + o; o += (size_t)5 * N;
  float* accDr   = W + o; o += (size_t)5 * N;
  float* accDh   = W + o; o += (size_t)5 * N;
  float* Zg      = W + o; o += (size_t)5 * N;
  float* Pf      = W + o; o += (size_t)20 * N;
  float* Pb      = W + o; o += (size_t)20 * N;
  float* Qf      = W + o; o += (size_t)20 * N;
  float* Qb      = W + o; o += (size_t)20 * N;
  float* Rf      = W + o; o += (size_t)10 * N;
  float* Rb      = W + o; o += (size_t)10 * N;
  float* WpackA  = W + o; o += 2000;
  float* WpackC  = W + o; o += 1000;

  // Phase-C aliases (regions free by then)
  float* Pfh = Pf; float* Pbh = Pb;
  float* Qfh = Qf; float* Qbh = Qb;
  float* Rfh = Rf; float* Rbh = Rb;

  const int EB = (E + 255) / 256;
  const int NB = (N + 255) / 256;

  // 1. packed weights (independent)
  prep_weights<<<8, 256, 0, stream>>>(Wz, Wr, Wh, WpackA, WpackC);

  // 2. zero degree/count block, then degrees + histogram
  hipMemsetAsync(deg_out, 0, (size_t)4 * N * sizeof(float), stream);
  degcnt_kernel<<<EB, 256, 0, stream>>>(ei, ew, deg_out, deg_in,
                                        cnt_dst, cnt_src, E);

  // 3. exclusive scans -> row starts + cursors
  scan_kernel<<<2, 1024, 0, stream>>>(cnt_dst, cnt_src, rs_fwd, cur_fwd,
                                      rs_bwd, cur_bwd, N);

  // 4. scatter edges into CSRs (also writes output A)
  scatter_kernel<<<EB, 256, 0, stream>>>(ei, ew, deg_out, deg_in,
                                         cur_fwd, cur_bwd,
                                         adj_fwd, adj_bwd, wf_out, E);

  // 5. node phase A
  nodeA_kernel<<<NB, 256, 0, stream>>>(x, W1, b1, W2, b2, bz, br, WpackA,
                                       h1, accDz, accDr, Pf, Pb, N);

  // 6. phase-A propagation (gather, no atomics)
  gprop_kernel<20><<<NB, 256, 0, stream>>>(rs_fwd, adj_fwd, Pf, 20, Qf, N);
  gprop_kernel<20><<<NB, 256, 0, stream>>>(rs_bwd, adj_bwd, Pb, 20, Qb, N);
  gprop_kernel<10><<<NB, 256, 0, stream>>>(rs_fwd, adj_fwd, Qf + 10, 20, Rf, N);
  gprop_kernel<10><<<NB, 256, 0, stream>>>(rs_bwd, adj_bwd, Qb + 10, 20, Rb, N);

  // 7. gates + XHr projections
  nodeB_kernel<<<NB, 256, 0, stream>>>(x, h1, accDz, accDr, Qf, Qb, Rf, Rb,
                                       bh, WpackC, Zg, accDh, Pfh, Pbh, N);

  // 8. phase-C propagation
  gprop_kernel<10><<<NB, 256, 0, stream>>>(rs_fwd, adj_fwd, Pfh, 10, Qfh, N);
  gprop_kernel<10><<<NB, 256, 0, stream>>>(rs_bwd, adj_bwd, Pbh, 10, Qbh, N);
  gprop_kernel<5><<<NB, 256, 0, stream>>>(rs_fwd, adj_fwd, Qfh + 5, 10, Rfh, N);
  gprop_kernel<5><<<NB, 256, 0, stream>>>(rs_bwd, adj_bwd, Qbh + 5, 10, Rbh, N);

  // 9. final
  nodeC_kernel<<<NB, 256, 0, stream>>>(h1, Zg, accDh, Qfh, Qbh, Rfh, Rbh,
                                       Wl, bl, y_out, N);
}

// Round 3
// 556.878 us; speedup vs baseline: 13.6431x; 2.0090x over previous
//
#include <hip/hip_runtime.h>

#define F_IN 35
#define F_OUT 5
#define HID 100
#define BSH 8              // 256 node-ids per bucket
#define BMSK 255
#define MAXB 512           // max buckets (requires N <= 131072)

// ---------------------------------------------------------------------------
// Weight prep: packed/combined projection matrices.
// dconv(X,W,b) = X@(W00+W10-W02-W12) + Pf(X@W01) + Pb(X@W11)
//               + 2*Pf(Pf(X@W02)) + 2*Pb(Pb(X@W12)) + b
// WpackA [40 x 50]: cols 0-4 Dz, 5-9 Dr, 10-14 Fz1, 15-19 Fr1, 20-24 Fz2,
//                   25-29 Fr2, 30-34 Bz1, 35-39 Br1, 40-44 Bz2, 45-49 Br2
// WpackC [40 x 25]: cols 0-4 Dh, 5-9 Fh1, 10-14 Fh2, 15-19 Bh1, 20-24 Bh2
// ---------------------------------------------------------------------------
__global__ __launch_bounds__(256) void prep_weights(
    const float* __restrict__ Wz, const float* __restrict__ Wr,
    const float* __restrict__ Wh,
    float* __restrict__ WpackA, float* __restrict__ WpackC) {
  int t = blockIdx.x * blockDim.x + threadIdx.x;
  if (t < 40 * 50) {
    int i = t / 50, c = t % 50;
    auto W = [&](const float* Wp, int d, int k, int o) {
      return Wp[((d * 3 + k) * 40 + i) * 5 + o];
    };
    float v;
    if (c < 5)       v = W(Wz,0,0,c)    + W(Wz,1,0,c)    - W(Wz,0,2,c)    - W(Wz,1,2,c);
    else if (c < 10) v = W(Wr,0,0,c-5)  + W(Wr,1,0,c-5)  - W(Wr,0,2,c-5)  - W(Wr,1,2,c-5);
    else if (c < 15) v = W(Wz,0,1,c-10);
    else if (c < 20) v = W(Wr,0,1,c-15);
    else if (c < 25) v = W(Wz,0,2,c-20);
    else if (c < 30) v = W(Wr,0,2,c-25);
    else if (c < 35) v = W(Wz,1,1,c-30);
    else if (c < 40) v = W(Wr,1,1,c-35);
    else if (c < 45) v = W(Wz,1,2,c-40);
    else             v = W(Wr,1,2,c-45);
    WpackA[i * 50 + c] = v;
  }
  if (t < 40 * 25) {
    int i = t / 25, c = t % 25;
    auto W = [&](const float* Wp, int d, int k, int o) {
      return Wp[((d * 3 + k) * 40 + i) * 5 + o];
    };
    float v;
    if (c < 5)       v = W(Wh,0,0,c)    + W(Wh,1,0,c)    - W(Wh,0,2,c)    - W(Wh,1,2,c);
    else if (c < 10) v = W(Wh,0,1,c-5);
    else if (c < 15) v = W(Wh,0,2,c-10);
    else if (c < 20) v = W(Wh,1,1,c-15);
    else             v = W(Wh,1,2,c-20);
    WpackC[i * 25 + c] = v;
  }
}

// ---------------------------------------------------------------------------
// Build step 1: bucket histograms (LDS pre-aggregated; ~100K global atomics)
// fwd CSR keyed by dst; bwd CSR keyed by src.
// ---------------------------------------------------------------------------
__global__ __launch_bounds__(256) void hist_kernel(
    const int* __restrict__ ei, int* __restrict__ bcnt_f,
    int* __restrict__ bcnt_b, int E) {
  __shared__ int h[2 * MAXB];
  for (int j = threadIdx.x; j < 2 * MAXB; j += 256) h[j] = 0;
  __syncthreads();
  for (int e = blockIdx.x * 256 + threadIdx.x; e < E; e += gridDim.x * 256) {
    int s = ei[e], d = ei[E + e];
    atomicAdd(&h[d >> BSH], 1);
    atomicAdd(&h[MAXB + (s >> BSH)], 1);
  }
  __syncthreads();
  for (int j = threadIdx.x; j < 2 * MAXB; j += 256) {
    int v = h[j];
    if (v) {
      if (j < MAXB) atomicAdd(&bcnt_f[j], v);
      else          atomicAdd(&bcnt_b[j - MAXB], v);
    }
  }
}

// ---------------------------------------------------------------------------
// Build step 2: bucket exclusive scan -> bases + cursors; also rs[N]=E.
// ---------------------------------------------------------------------------
__global__ __launch_bounds__(512) void scanb_kernel(
    const int* __restrict__ bcnt_f, const int* __restrict__ bcnt_b,
    int* __restrict__ bbase_f, int* __restrict__ bbase_b,
    int* __restrict__ bcur_f, int* __restrict__ bcur_b,
    int* __restrict__ rs_f, int* __restrict__ rs_b,
    int nbuck, int N, int E) {
  __shared__ int s0[MAXB], s1[MAXB];
  int t = threadIdx.x;
  s0[t] = (t < nbuck) ? bcnt_f[t] : 0;
  s1[t] = (t < nbuck) ? bcnt_b[t] : 0;
  __syncthreads();
  for (int off = 1; off < MAXB; off <<= 1) {
    int a = (t >= off) ? s0[t - off] : 0;
    int b = (t >= off) ? s1[t - off] : 0;
    __syncthreads();
    s0[t] += a; s1[t] += b;
    __syncthreads();
  }
  bbase_f[t + 1] = s0[t];
  bbase_b[t + 1] = s1[t];
  bcur_f[t] = t ? s0[t - 1] : 0;
  bcur_b[t] = t ? s1[t - 1] : 0;
  if (t == 0) { bbase_f[0] = 0; bbase_b[0] = 0; rs_f[N] = E; rs_b[N] = E; }
}

// ---------------------------------------------------------------------------
// Build step 3: bin edges into compact bucket regions (block-local LDS
// cursors; one global atomic per block x nonzero bucket). Item packs the
// key-node's low 8 bits into bits 17-24 above the 17-bit other-endpoint id.
// ---------------------------------------------------------------------------
__global__ __launch_bounds__(256) void passB_kernel(
    const int* __restrict__ ei, const float* __restrict__ w,
    int* __restrict__ bcur_f, int* __restrict__ bcur_b,
    int2* __restrict__ binned_f, int2* __restrict__ binned_b, int E) {
  __shared__ int hf[MAXB], hb[MAXB], cf[MAXB], cb_[MAXB];
  int tid = threadIdx.x;
  for (int j = tid; j < MAXB; j += 256) { hf[j] = 0; hb[j] = 0; cf[j] = 0; cb_[j] = 0; }
  __syncthreads();
  size_t c0 = (size_t)blockIdx.x * E / gridDim.x;
  size_t c1 = (size_t)(blockIdx.x + 1) * E / gridDim.x;
  for (size_t e = c0 + tid; e < c1; e += 256) {
    int s = ei[e], d = ei[E + e];
    atomicAdd(&hf[d >> BSH], 1);
    atomicAdd(&hb[s >> BSH], 1);
  }
  __syncthreads();
  for (int j = tid; j < MAXB; j += 256) {
    int v = hf[j];
    if (v) hf[j] = atomicAdd(&bcur_f[j], v);
    int u = hb[j];
    if (u) hb[j] = atomicAdd(&bcur_b[j], u);
  }
  __syncthreads();
  for (size_t e = c0 + tid; e < c1; e += 256) {
    int s = ei[e], d = ei[E + e];
    int wb = __float_as_int(w[e]);
    int bf = d >> BSH;
    int pf = hf[bf] + atomicAdd(&cf[bf], 1);
    binned_f[pf] = make_int2(s | ((d & BMSK) << 17), wb);
    int bb = s >> BSH;
    int pb = hb[bb] + atomicAdd(&cb_[bb], 1);
    binned_b[pb] = make_int2(d | ((s & BMSK) << 17), wb);
  }
}

// ---------------------------------------------------------------------------
// Build step 4: per-bucket CSR finalize. LDS per-node count + weight sum
// (row sums give degrees for free), LDS scan -> rowstarts, LDS-cursor
// scatter into final adjacency (writes confined to the bucket's region).
// fwd rows sum to deg_in; bwd rows sum to deg_out.
// ---------------------------------------------------------------------------
__global__ __launch_bounds__(256) void passC_kernel(
    const int2* __restrict__ binned_f, const int2* __restrict__ binned_b,
    const int* __restrict__ bbase_f, const int* __restrict__ bbase_b,
    int2* __restrict__ adj_f, int2* __restrict__ adj_b,
    int* __restrict__ rs_f, int* __restrict__ rs_b,
    float* __restrict__ inv_in, float* __restrict__ inv_out, int N) {
  int dir = blockIdx.y;
  const int2* binned = dir ? binned_b : binned_f;
  const int* bbase   = dir ? bbase_b  : bbase_f;
  int2* adj          = dir ? adj_b    : adj_f;
  int* rs            = dir ? rs_b     : rs_f;
  float* inv         = dir ? inv_out  : inv_in;
  int b = blockIdx.x;
  int base = bbase[b], end = bbase[b + 1];
  __shared__ int cnt[256]; __shared__ float wsum[256];
  __shared__ int loc[256]; __shared__ int cur[256];
  int tid = threadIdx.x;
  cnt[tid] = 0; wsum[tid] = 0.f; cur[tid] = 0;
  __syncthreads();
  for (int i = base + tid; i < end; i += 256) {
    int2 it = binned[i];
    int nl = (it.x >> 17) & BMSK;
    atomicAdd(&cnt[nl], 1);
    atomicAdd(&wsum[nl], __int_as_float(it.y));
  }
  __syncthreads();
  int v = cnt[tid];
  loc[tid] = v;
  __syncthreads();
  for (int off = 1; off < 256; off <<= 1) {
    int a = (tid >= off) ? loc[tid - off] : 0;
    __syncthreads();
    loc[tid] += a;
    __syncthreads();
  }
  int excl = loc[tid] - v;
  int node = (b << BSH) + tid;
  if (node < N) {
    rs[node] = base + excl;
    inv[node] = 1.f / fmaxf(wsum[tid], 1e-12f);
  }
  __syncthreads();
  loc[tid] = excl;
  __syncthreads();
  for (int i = base + tid; i < end; i += 256) {
    int2 it = binned[i];
    int nl = (it.x >> 17) & BMSK;
    int p = base + loc[nl] + atomicAdd(&cur[nl], 1);
    adj[p] = make_int2(it.x & 0x1FFFF, it.y);
  }
}

// ---------------------------------------------------------------------------
// Build step 5: normalize adjacency weights in place (gather inv_deg of the
// other endpoint; 400KB read-only, L2-resident) + emit w_fwd (output A).
// ---------------------------------------------------------------------------
__global__ __launch_bounds__(256) void finalize_kernel(
    const int* __restrict__ ei, const float* __restrict__ w,
    const float* __restrict__ inv_out, const float* __restrict__ inv_in,
    int2* __restrict__ adj_f, int2* __restrict__ adj_b,
    float* __restrict__ wf_out, int E) {
  for (int i = blockIdx.x * 256 + threadIdx.x; i < 3 * E; i += gridDim.x * 256) {
    if (i < E) {
      wf_out[i] = w[i] * inv_out[ei[i]];
    } else if (i < 2 * E) {
      int j = i - E;
      int2 a = adj_f[j];
      adj_f[j].y = __float_as_int(__int_as_float(a.y) * inv_out[a.x]);
    } else {
      int j = i - 2 * E;
      int2 a = adj_b[j];
      adj_b[j].y = __float_as_int(__int_as_float(a.y) * inv_in[a.x]);
    }
  }
}

// ---------------------------------------------------------------------------
// Gather propagation: out[n][0..C) = sum_{(m,w) in adj[n]} w * in[m][0..C)
// ---------------------------------------------------------------------------
template <int C>
__global__ __launch_bounds__(256) void gprop_kernel(
    const int* __restrict__ rowstart, const int2* __restrict__ adj,
    const float* __restrict__ in, int ldin,
    float* __restrict__ out, int N) {
  int n = blockIdx.x * blockDim.x + threadIdx.x;
  if (n >= N) return;
  int i0 = rowstart[n], i1 = rowstart[n + 1];
  float acc[C];
  #pragma unroll
  for (int c = 0; c < C; c++) acc[c] = 0.f;
  for (int i = i0; i < i1; i++) {
    int2 a = adj[i];
    float ww = __int_as_float(a.y);
    const float* row = in + (size_t)a.x * ldin;
    #pragma unroll
    for (int c = 0; c < C; c++) acc[c] = fmaf(ww, row[c], acc[c]);
  }
  float* orow = out + (size_t)n * C;
  #pragma unroll
  for (int c = 0; c < C; c++) orow[c] = acc[c];
}

// ---------------------------------------------------------------------------
// Node phase A: MLP (h1) + XH projections (direct terms + prop inputs)
// ---------------------------------------------------------------------------
__global__ __launch_bounds__(256) void nodeA_kernel(
    const float* __restrict__ x,
    const float* __restrict__ W1, const float* __restrict__ b1,
    const float* __restrict__ W2, const float* __restrict__ b2,
    const float* __restrict__ bz, const float* __restrict__ br,
    const float* __restrict__ WpackA,
    float* __restrict__ h1, float* __restrict__ accDz,
    float* __restrict__ accDr, float* __restrict__ Pf,
    float* __restrict__ Pb, int N) {
  int n = blockIdx.x * blockDim.x + threadIdx.x;
  if (n >= N) return;
  float xv[40];
  const float* xr = x + (size_t)n * F_IN;
  #pragma unroll
  for (int i = 0; i < F_IN; i++) xv[i] = xr[i];

  float h5[5];
  #pragma unroll
  for (int o = 0; o < 5; o++) h5[o] = b2[o];
  for (int hh = 0; hh < HID; hh++) {
    float t = b1[hh];
    #pragma unroll
    for (int i = 0; i < F_IN; i++) t += xv[i] * W1[i * HID + hh];
    t = fmaxf(t, 0.f);
    #pragma unroll
    for (int o = 0; o < 5; o++) h5[o] += t * W2[hh * 5 + o];
  }
  #pragma unroll
  for (int o = 0; o < 5; o++) {
    h1[(size_t)n * 5 + o] = h5[o];
    xv[F_IN + o] = h5[o];
  }

  float acc[50];
  #pragma unroll
  for (int c = 0; c < 50; c++) acc[c] = 0.f;
  for (int i = 0; i < 40; i++) {
    float xi = xv[i];
    #pragma unroll
    for (int c = 0; c < 50; c++) acc[c] += xi * WpackA[i * 50 + c];
  }
  #pragma unroll
  for (int o = 0; o < 5; o++) {
    accDz[(size_t)n * 5 + o] = acc[o] + bz[o];
    accDr[(size_t)n * 5 + o] = acc[5 + o] + br[o];
  }
  #pragma unroll
  for (int c = 0; c < 20; c++) Pf[(size_t)n * 20 + c] = acc[10 + c];
  #pragma unroll
  for (int c = 0; c < 20; c++) Pb[(size_t)n * 20 + c] = acc[30 + c];
}

// ---------------------------------------------------------------------------
// Node phase B: Z,R gates + XHr projections
// ---------------------------------------------------------------------------
__global__ __launch_bounds__(256) void nodeB_kernel(
    const float* __restrict__ x, const float* __restrict__ h1,
    const float* __restrict__ accDz, const float* __restrict__ accDr,
    const float* __restrict__ Qf, const float* __restrict__ Qb,
    const float* __restrict__ Rf, const float* __restrict__ Rb,
    const float* __restrict__ bh, const float* __restrict__ WpackC,
    float* __restrict__ Zg, float* __restrict__ accDh,
    float* __restrict__ Pfh, float* __restrict__ Pbh, int N) {
  int n = blockIdx.x * blockDim.x + threadIdx.x;
  if (n >= N) return;
  float r[5];
  #pragma unroll
  for (int o = 0; o < 5; o++) {
    float zp = accDz[(size_t)n * 5 + o] + Qf[(size_t)n * 20 + o] +
               Qb[(size_t)n * 20 + o] + 2.f * Rf[(size_t)n * 10 + o] +
               2.f * Rb[(size_t)n * 10 + o];
    float rp = accDr[(size_t)n * 5 + o] + Qf[(size_t)n * 20 + 5 + o] +
               Qb[(size_t)n * 20 + 5 + o] + 2.f * Rf[(size_t)n * 10 + 5 + o] +
               2.f * Rb[(size_t)n * 10 + 5 + o];
    float z = 1.f / (1.f + __expf(-zp));
    r[o] = 1.f / (1.f + __expf(-rp));
    Zg[(size_t)n * 5 + o] = z;
  }
  float xv[40];
  const float* xr = x + (size_t)n * F_IN;
  #pragma unroll
  for (int i = 0; i < F_IN; i++) xv[i] = xr[i];
  #pragma unroll
  for (int o = 0; o < 5; o++) xv[F_IN + o] = h1[(size_t)n * 5 + o] * r[o];

  float acc[25];
  #pragma unroll
  for (int c = 0; c < 25; c++) acc[c] = 0.f;
  for (int i = 0; i < 40; i++) {
    float xi = xv[i];
    #pragma unroll
    for (int c = 0; c < 25; c++) acc[c] += xi * WpackC[i * 25 + c];
  }
  #pragma unroll
  for (int o = 0; o < 5; o++) accDh[(size_t)n * 5 + o] = acc[o] + bh[o];
  #pragma unroll
  for (int c = 0; c < 10; c++) {
    Pfh[(size_t)n * 10 + c] = acc[5 + c];
    Pbh[(size_t)n * 10 + c] = acc[15 + c];
  }
}

// ---------------------------------------------------------------------------
// Node phase C: H_tilde, H, y
// ---------------------------------------------------------------------------
__global__ __launch_bounds__(256) void nodeC_kernel(
    const float* __restrict__ h1, const float* __restrict__ Zg,
    const float* __restrict__ accDh,
    const float* __restrict__ Qfh, const float* __restrict__ Qbh,
    const float* __restrict__ Rfh, const float* __restrict__ Rbh,
    const float* __restrict__ Wl, const float* __restrict__ bl,
    float* __restrict__ y, int N) {
  int n = blockIdx.x * blockDim.x + threadIdx.x;
  if (n >= N) return;
  float acc = bl[0];
  #pragma unroll
  for (int o = 0; o < 5; o++) {
    float pre = accDh[(size_t)n * 5 + o] + Qfh[(size_t)n * 10 + o] +
                Qbh[(size_t)n * 10 + o] + 2.f * Rfh[(size_t)n * 5 + o] +
                2.f * Rbh[(size_t)n * 5 + o];
    float ht = tanhf(pre);
    float z = Zg[(size_t)n * 5 + o];
    float H = z * h1[(size_t)n * 5 + o] + (1.f - z) * ht;
    acc += fmaxf(H, 0.f) * Wl[o];
  }
  y[n] = acc;
}

// ---------------------------------------------------------------------------
extern "C" void kernel_launch(void* const* d_in, const int* in_sizes, int n_in,
                              void* d_out, int out_size, void* d_ws, size_t ws_size,
                              hipStream_t stream) {
  const float* x  = (const float*)d_in[0];
  const int*   ei = (const int*)d_in[1];
  const float* ew = (const float*)d_in[2];
  const float* W1 = (const float*)d_in[3];
  const float* b1 = (const float*)d_in[4];
  const float* W2 = (const float*)d_in[5];
  const float* b2 = (const float*)d_in[6];
  const float* Wz = (const float*)d_in[7];
  const float* bz = (const float*)d_in[8];
  const float* Wr = (const float*)d_in[9];
  const float* br = (const float*)d_in[10];
  const float* Wh = (const float*)d_in[11];
  const float* bh = (const float*)d_in[12];
  const float* Wl = (const float*)d_in[13];
  const float* bl = (const float*)d_in[14];

  const int N = in_sizes[0] / F_IN;
  const int E = in_sizes[2];
  const int nbuck = ((N - 1) >> BSH) + 1;   // N <= 131072 assumed

  float* out = (float*)d_out;
  float* y_out  = out;          // [N]
  float* wf_out = out + N;      // [E]  == output A

  // Workspace layout (4-byte words; keep int2 regions 8B-aligned)
  float* W = (float*)d_ws;
  size_t o = 0;
  int* bcnt_f  = (int*)(W + o); o += MAXB;       // | zeroed as one block
  int* bcnt_b  = (int*)(W + o); o += MAXB;       // |
  int* bbase_f = (int*)(W + o); o += MAXB + 2;
  int* bbase_b = (int*)(W + o); o += MAXB + 2;
  int* bcur_f  = (int*)(W + o); o += MAXB;
  int* bcur_b  = (int*)(W + o); o += MAXB;
  int* rs_f    = (int*)(W + o); o += (size_t)N + 1;
  int* rs_b    = (int*)(W + o); o += (size_t)N + 1;
  float* inv_out = W + o; o += N;
  float* inv_in  = W + o; o += N;
  o = (o + 1) & ~(size_t)1;
  int2* adj_f  = (int2*)(W + o); o += 2 * (size_t)E;
  int2* adj_b  = (int2*)(W + o); o += 2 * (size_t)E;
  float* h1    = W + o; o += (size_t)5 * N;
  float* accDz = W + o; o += (size_t)5 * N;
  float* accDr = W + o; o += (size_t)5 * N;
  float* accDh = W + o; o += (size_t)5 * N;
  float* Zg    = W + o; o += (size_t)5 * N;
  o = (o + 1) & ~(size_t)1;
  float* Pf    = W + o; o += (size_t)20 * N;
  float* Pb    = W + o; o += (size_t)20 * N;
  float* Qf    = W + o; o += (size_t)20 * N;
  float* Qb    = W + o; o += (size_t)20 * N;
  float* Rf    = W + o; o += (size_t)10 * N;
  float* Rb    = W + o; o += (size_t)10 * N;
  float* WpackA = W + o; o += 2000;
  float* WpackC = W + o; o += 1000;

  // binned scratch aliases Pf..Qb (consumed by passC before nodeA writes Pf);
  // needs 4E words <= 80N words.
  int2* binned_f = (int2*)Pf;
  int2* binned_b = binned_f + E;

  // Phase-C aliases (regions free by then)
  float* Pfh = Pf; float* Pbh = Pb;
  float* Qfh = Qf; float* Qbh = Qb;
  float* Rfh = Rf; float* Rbh = Rb;

  const int NB = (N + 255) / 256;

  // 1. packed weights (independent)
  prep_weights<<<8, 256, 0, stream>>>(Wz, Wr, Wh, WpackA, WpackC);

  // 2. CSR build: hist -> scan -> bin -> finalize-per-bucket -> normalize
  hipMemsetAsync(bcnt_f, 0, 2 * MAXB * sizeof(int), stream);
  hist_kernel<<<128, 256, 0, stream>>>(ei, bcnt_f, bcnt_b, E);
  scanb_kernel<<<1, MAXB, 0, stream>>>(bcnt_f, bcnt_b, bbase_f, bbase_b,
                                       bcur_f, bcur_b, rs_f, rs_b,
                                       nbuck, N, E);
  passB_kernel<<<128, 256, 0, stream>>>(ei, ew, bcur_f, bcur_b,
                                        binned_f, binned_b, E);
  passC_kernel<<<dim3(nbuck, 2), 256, 0, stream>>>(
      binned_f, binned_b, bbase_f, bbase_b, adj_f, adj_b,
      rs_f, rs_b, inv_in, inv_out, N);
  finalize_kernel<<<2048, 256, 0, stream>>>(ei, ew, inv_out, inv_in,
                                            adj_f, adj_b, wf_out, E);

  // 3. node phase A
  nodeA_kernel<<<NB, 256, 0, stream>>>(x, W1, b1, W2, b2, bz, br, WpackA,
                                       h1, accDz, accDr, Pf, Pb, N);

  // 4. phase-A propagation (gather, no atomics)
  gprop_kernel<20><<<NB, 256, 0, stream>>>(rs_f, adj_f, Pf, 20, Qf, N);
  gprop_kernel<20><<<NB, 256, 0, stream>>>(rs_b, adj_b, Pb, 20, Qb, N);
  gprop_kernel<10><<<NB, 256, 0, stream>>>(rs_f, adj_f, Qf + 10, 20, Rf, N);
  gprop_kernel<10><<<NB, 256, 0, stream>>>(rs_b, adj_b, Qb + 10, 20, Rb, N);

  // 5. gates + XHr projections
  nodeB_kernel<<<NB, 256, 0, stream>>>(x, h1, accDz, accDr, Qf, Qb, Rf, Rb,
                                       bh, WpackC, Zg, accDh, Pfh, Pbh, N);

  // 6. phase-C propagation
  gprop_kernel<10><<<NB, 256, 0, stream>>>(rs_f, adj_f, Pfh, 10, Qfh, N);
  gprop_kernel<10><<<NB, 256, 0, stream>>>(rs_b, adj_b, Pbh, 10, Qbh, N);
  gprop_kernel<5><<<NB, 256, 0, stream>>>(rs_f, adj_f, Qfh + 5, 10, Rfh, N);
  gprop_kernel<5><<<NB, 256, 0, stream>>>(rs_b, adj_b, Qbh + 5, 10, Rbh, N);

  // 7. final
  nodeC_kernel<<<NB, 256, 0, stream>>>(h1, Zg, accDh, Qfh, Qbh, Rfh, Rbh,
                                       Wl, bl, y_out, N);
}